// Round 4
// baseline (247.320 us; speedup 1.0000x reference)
//
#include <hip/hip_runtime.h>
#include <math.h>

// Problem constants: B=1024, N=200, E=128, fp32.
constexpr int Bc = 1024;
constexpr int Nc = 200;
constexpr int Ec = 128;
constexpr int TROWS  = 32;   // rows per block
constexpr int CHUNKS = 7;    // ceil(200/32) -> last chunk has 8 valid rows
constexpr int RPAD   = 132;  // floats per LDS row: 128 + 4 pad (528 B stride,
                             // makes ds_read_b128 exactly 2-way = free)

typedef const __attribute__((address_space(1))) void GVoid;
typedef __attribute__((address_space(3)))       void LVoid;

// K1: grid (B, CHUNKS) x 256. Stage 32 rows of m and m_c (32 KB) into LDS via
// async global_load_lds (16 x 512B per wave, fire-and-forget: zero VGPR cost,
// the register allocator cannot serialize it like it did in R2/R3 where
// VGPR_Count=36 proved the 10-load batch got serialized -> 1 load in flight).
// Then thread t reduces local row t>>3 (16 elems) + 3-stage 8-lane shuffle.
__global__ __launch_bounds__(256, 4) void dist_part(
    const float* __restrict__ q,      // (B,E)
    const float* __restrict__ q_p,    // (B,E)
    const float* __restrict__ m,      // (B,N,E)
    const float* __restrict__ m_c,    // (B,N,E)
    const float* __restrict__ A1,     // (E)
    const float* __restrict__ A2,     // (E)
    const float* __restrict__ biases, // (B,N)
    const float* __restrict__ mask,   // (B,N)
    float* __restrict__ xs_ws,        // (B,N) softmax logits -> d_ws
    float* __restrict__ os_out)       // (B,N) out_dist*mask  -> d_out
{
    __shared__ float smem[2 * TROWS * RPAD];   // 33 KB -> 4 blocks/CU

    const int b     = blockIdx.x;
    const int chunk = blockIdx.y;
    const int tid   = threadIdx.x;
    const int w     = tid >> 6;   // wave 0..3
    const int lane  = tid & 63;
    const int n0    = chunk * TROWS;

    const float* mb  = m   + ((size_t)b * Nc + n0) * Ec;
    const float* mcb = m_c + ((size_t)b * Nc + n0) * Ec;

    // Async staging: wave w stages local rows w*8..w*8+7 for both arrays.
    // Half-wave predicated (32 lanes x 16 B = one 512 B row per instruction)
    // so each row lands at its padded LDS offset.
    if (lane < 32) {
#pragma unroll
        for (int j = 0; j < 8; ++j) {
            const int r = w * 8 + j;
            if (n0 + r < Nc) {
                __builtin_amdgcn_global_load_lds(
                    (GVoid*)(mb + (size_t)r * Ec + lane * 4),
                    (LVoid*)&smem[r * RPAD], 16, 0, 0);
                __builtin_amdgcn_global_load_lds(
                    (GVoid*)(mcb + (size_t)r * Ec + lane * 4),
                    (LVoid*)&smem[(TROWS + r) * RPAD], 16, 0, 0);
            }
        }
    }

    // Meanwhile: per-thread slices of q/q_p/A1/A2 (L1-hot broadcasts).
    const int row = tid >> 3;    // local row 0..31 (wave w owns rows it staged)
    const int sub = tid & 7;     // 8 threads/row, 16 elems each
    const int e0  = sub * 16;

    float4 q4[4], qp4[4], a14[4], a24[4];
#pragma unroll
    for (int k = 0; k < 4; ++k) {
        q4[k]  = *reinterpret_cast<const float4*>(q   + (size_t)b * Ec + e0 + k * 4);
        qp4[k] = *reinterpret_cast<const float4*>(q_p + (size_t)b * Ec + e0 + k * 4);
        a14[k] = *reinterpret_cast<const float4*>(A1  + e0 + k * 4);
        a24[k] = *reinterpret_cast<const float4*>(A2  + e0 + k * 4);
    }

    __syncthreads();   // vmcnt(0) drain + compiler memory barrier (LDS writes
                       // from global_load_lds are invisible to alias analysis)

    const int n = n0 + row;
    float sa = 0.f, so = 0.f;
    if (n < Nc) {
#pragma unroll
        for (int k = 0; k < 4; ++k) {
            const float4 m4  = *reinterpret_cast<const float4*>(
                &smem[row * RPAD + e0 + k * 4]);
            const float4 mc4 = *reinterpret_cast<const float4*>(
                &smem[(TROWS + row) * RPAD + e0 + k * 4]);
#define COMP(c) {                                                          \
            float t1 = (q4[k].c  - m4.c)  * a14[k].c; sa = fmaf(t1, t1, sa); \
            float t2 = (qp4[k].c - m4.c)  * a24[k].c; sa = fmaf(t2, t2, sa); \
            float u1 = (q4[k].c  - mc4.c) * a14[k].c; so = fmaf(u1, u1, so); \
            float u2 = (qp4[k].c - mc4.c) * a24[k].c; so = fmaf(u2, u2, so); }
            COMP(x) COMP(y) COMP(z) COMP(w)
#undef COMP
        }
    }

    // Reduce across the 8 threads of this row (xor 1,2,4 stays in-group).
    sa += __shfl_xor(sa, 1);  so += __shfl_xor(so, 1);
    sa += __shfl_xor(sa, 2);  so += __shfl_xor(so, 2);
    sa += __shfl_xor(sa, 4);  so += __shfl_xor(so, 4);

    if (sub == 0 && n < Nc) {
        const float bb = biases[(size_t)b * Nc + n];
        const float mk = mask[(size_t)b * Nc + n];
        xs_ws[(size_t)b * Nc + n]  = -(sa + 2.f * bb) * mk;
        os_out[(size_t)b * Nc + n] =  (so + 2.f * bb) * mk;
    }
}

// K2: one block per batch; softmax over the 200 logits, scale os, write out.
__global__ __launch_bounds__(256) void softmax_fin(
    const float* __restrict__ xs_ws,  // (B,N) logits
    float* __restrict__ out)          // (B,N) in: out_dist*mask, out: result
{
    const int b   = blockIdx.x;
    const int tid = threadIdx.x;
    __shared__ float red_s[8];

    const float x  = (tid < Nc) ? xs_ws[(size_t)b * Nc + tid] : -INFINITY;
    const float os = (tid < Nc) ? out[(size_t)b * Nc + tid]   : 0.f;

    float wmax = x;
#pragma unroll
    for (int off = 32; off > 0; off >>= 1)
        wmax = fmaxf(wmax, __shfl_xor(wmax, off));
    if ((tid & 63) == 0) red_s[tid >> 6] = wmax;
    __syncthreads();
    const float gmax = fmaxf(fmaxf(red_s[0], red_s[1]), fmaxf(red_s[2], red_s[3]));

    const float ex = (tid < Nc) ? expf(x - gmax) : 0.f;
    float wsum = ex;
#pragma unroll
    for (int off = 32; off > 0; off >>= 1)
        wsum += __shfl_xor(wsum, off);
    if ((tid & 63) == 0) red_s[4 + (tid >> 6)] = wsum;
    __syncthreads();
    const float gsum = (red_s[4] + red_s[5]) + (red_s[6] + red_s[7]);

    if (tid < Nc)
        out[(size_t)b * Nc + tid] = os * (ex / gsum);
}

extern "C" void kernel_launch(void* const* d_in, const int* in_sizes, int n_in,
                              void* d_out, int out_size, void* d_ws, size_t ws_size,
                              hipStream_t stream) {
    const float* q      = (const float*)d_in[0];
    const float* q_p    = (const float*)d_in[1];
    const float* m      = (const float*)d_in[2];
    const float* m_c    = (const float*)d_in[3];
    const float* A1     = (const float*)d_in[4];
    const float* A2     = (const float*)d_in[5];
    const float* biases = (const float*)d_in[6];
    const float* mask   = (const float*)d_in[7];
    float* out   = (float*)d_out;
    float* xs_ws = (float*)d_ws;   // Bc*Nc floats = 800 KiB

    dim3 grid1(Bc, CHUNKS);
    dist_part<<<grid1, 256, 0, stream>>>(q, q_p, m, m_c, A1, A2, biases, mask,
                                         xs_ws, out);
    softmax_fin<<<Bc, 256, 0, stream>>>(xs_ws, out);
}

// Round 5
// 244.787 us; speedup vs baseline: 1.0103x; 1.0103x over previous
//
#include <hip/hip_runtime.h>
#include <math.h>

// Problem constants: B=1024, N=200, E=128, fp32.
constexpr int Bc = 1024;
constexpr int Nc = 200;
constexpr int Ec = 128;
constexpr int PAIRS = Nc / 2;          // 100 row-pairs per batch
constexpr int WPB   = 8;               // waves per batch
constexpr int NWAVE = Bc * WPB;        // 8192 waves
constexpr int NBLK  = NWAVE / 4;       // 2048 blocks of 256 threads

// K1: persistent streaming waves. 32 waves/CU (vs <=16 in R1-R4), each wave
// owns batch b = gw>>3 and iterates ~12-13 row-pairs in a grid-stride loop
// with a depth-1 software pipeline: next pair's 2 KB of loads issue before
// the current pair's shuffle-reduce. Loads flow continuously (m13-copy-like
// steady state); q/q_p/A1/A2 load once per wave; no LDS, no barriers.
__global__ __launch_bounds__(256, 8) void dist_part(
    const float* __restrict__ q,      // (B,E)
    const float* __restrict__ q_p,    // (B,E)
    const float* __restrict__ m,      // (B,N,E)
    const float* __restrict__ m_c,    // (B,N,E)
    const float* __restrict__ biases, // (B,N)
    const float* __restrict__ mask,   // (B,N)
    const float* __restrict__ A1,     // (E)
    const float* __restrict__ A2,     // (E)
    float* __restrict__ xs_ws,        // (B,N) softmax logits -> d_ws
    float* __restrict__ os_out)       // (B,N) out_dist*mask  -> d_out
{
    const int tid  = threadIdx.x;
    const int gw   = blockIdx.x * 4 + (tid >> 6);  // global wave id 0..8191
    const int lane = tid & 63;
    const int b    = gw >> 3;        // 8 waves per batch
    const int wj   = gw & 7;         // this wave's pair offset within b

    // Lane layout per pair j: rows n = 2j + (lane>>5); e0 = (lane&31)*4.
    const int rl  = lane >> 5;       // 0 or 1: which row of the pair
    const int e0  = (lane & 31) * 4;

    const float4 qv  = *reinterpret_cast<const float4*>(q   + (size_t)b * Ec + e0);
    const float4 qpv = *reinterpret_cast<const float4*>(q_p + (size_t)b * Ec + e0);
    const float4 a1v = *reinterpret_cast<const float4*>(A1  + e0);
    const float4 a2v = *reinterpret_cast<const float4*>(A2  + e0);

    const float* mb  = m   + (size_t)b * Nc * Ec;
    const float* mcb = m_c + (size_t)b * Nc * Ec;

    // Pair indices for this wave: j = wj, wj+8, wj+16, ... (<100).
    // Wave-uniform trip count (wj is uniform within the wave).
    int j = wj;
    const size_t off0 = ((size_t)(2 * j + rl)) * Ec + e0;
    float4 mA  = *reinterpret_cast<const float4*>(mb  + off0);
    float4 mcA = *reinterpret_cast<const float4*>(mcb + off0);

    while (j < PAIRS) {
        const int jn = j + WPB;
        float4 mB, mcB;
        if (jn < PAIRS) {   // prefetch next pair (issues before the reduce)
            const size_t offn = ((size_t)(2 * jn + rl)) * Ec + e0;
            mB  = *reinterpret_cast<const float4*>(mb  + offn);
            mcB = *reinterpret_cast<const float4*>(mcb + offn);
        }

        float sa = 0.f, so = 0.f;
#define COMP(c) {                                                      \
        float t1 = (qv.c  - mA.c)  * a1v.c;  sa = fmaf(t1, t1, sa);    \
        float t2 = (qpv.c - mA.c)  * a2v.c;  sa = fmaf(t2, t2, sa);    \
        float u1 = (qv.c  - mcA.c) * a1v.c;  so = fmaf(u1, u1, so);    \
        float u2 = (qpv.c - mcA.c) * a2v.c;  so = fmaf(u2, u2, so); }
        COMP(x) COMP(y) COMP(z) COMP(w)
#undef COMP

        // Reduce within each 32-lane half (rows are independent per half).
#pragma unroll
        for (int off = 16; off > 0; off >>= 1) {
            sa += __shfl_xor(sa, off);
            so += __shfl_xor(so, off);
        }

        if ((lane & 31) == 0) {
            const int n = 2 * j + rl;
            const float bb = biases[(size_t)b * Nc + n];
            const float mk = mask[(size_t)b * Nc + n];
            xs_ws[(size_t)b * Nc + n]  = -(sa + 2.f * bb) * mk;
            os_out[(size_t)b * Nc + n] =  (so + 2.f * bb) * mk;
        }

        mA = mB; mcA = mcB;
        j = jn;
    }
}

// K2: one block per batch; softmax over the 200 logits, scale os, write out.
__global__ __launch_bounds__(256) void softmax_fin(
    const float* __restrict__ xs_ws,  // (B,N) logits
    float* __restrict__ out)          // (B,N) in: out_dist*mask, out: result
{
    const int b   = blockIdx.x;
    const int tid = threadIdx.x;
    __shared__ float red_s[8];

    const float x  = (tid < Nc) ? xs_ws[(size_t)b * Nc + tid] : -INFINITY;
    const float os = (tid < Nc) ? out[(size_t)b * Nc + tid]   : 0.f;

    float wmax = x;
#pragma unroll
    for (int off = 32; off > 0; off >>= 1)
        wmax = fmaxf(wmax, __shfl_xor(wmax, off));
    if ((tid & 63) == 0) red_s[tid >> 6] = wmax;
    __syncthreads();
    const float gmax = fmaxf(fmaxf(red_s[0], red_s[1]), fmaxf(red_s[2], red_s[3]));

    const float ex = (tid < Nc) ? expf(x - gmax) : 0.f;
    float wsum = ex;
#pragma unroll
    for (int off = 32; off > 0; off >>= 1)
        wsum += __shfl_xor(wsum, off);
    if ((tid & 63) == 0) red_s[4 + (tid >> 6)] = wsum;
    __syncthreads();
    const float gsum = (red_s[4] + red_s[5]) + (red_s[6] + red_s[7]);

    if (tid < Nc)
        out[(size_t)b * Nc + tid] = os * (ex / gsum);
}

extern "C" void kernel_launch(void* const* d_in, const int* in_sizes, int n_in,
                              void* d_out, int out_size, void* d_ws, size_t ws_size,
                              hipStream_t stream) {
    const float* q      = (const float*)d_in[0];
    const float* q_p    = (const float*)d_in[1];
    const float* m      = (const float*)d_in[2];
    const float* m_c    = (const float*)d_in[3];
    const float* A1     = (const float*)d_in[4];
    const float* A2     = (const float*)d_in[5];
    const float* biases = (const float*)d_in[6];
    const float* mask   = (const float*)d_in[7];
    float* out   = (float*)d_out;
    float* xs_ws = (float*)d_ws;   // Bc*Nc floats = 800 KiB

    dist_part<<<NBLK, 256, 0, stream>>>(q, q_p, m, m_c, biases, mask, A1, A2,
                                        xs_ws, out);
    softmax_fin<<<Bc, 256, 0, stream>>>(xs_ws, out);
}

// Round 6
// 242.280 us; speedup vs baseline: 1.0208x; 1.0104x over previous
//
#include <hip/hip_runtime.h>
#include <math.h>

// Problem constants: B=1024, N=200, E=128, fp32.
constexpr int Bc = 1024;
constexpr int Nc = 200;
constexpr int Ec = 128;
constexpr int HALF = 100;   // rows per block (grid.y = 2 halves per batch)
constexpr int ITER = 25;    // streaming iters per wave: 50 rows, 2 rows/iter

typedef float vfloat4 __attribute__((ext_vector_type(4)));

// K1: copy-style streaming. Expansion: sum_e (A(q-m))^2 = C - 2 u.m + s.m^2,
// so per float4 each lane computes a PRIVATE partial p = sum m*(s*m - 2u)
// and ds_writes it — the streaming loop has NO shuffles, NO barriers, NO
// cross-iteration deps (R1-R5 all pinned at 2.44 TB/s with a serial
// shuffle/barrier chain per iteration; m13's 6.3 TB/s copy has none).
// Wave w: arr = w>>1 (m / m_c), half = w&1; 50 consecutive rows = 25.6 KB
// sequential stream, 1 KB contiguous per wave-instruction.
// Phase 2 (decoupled): reduce 32 lane-partials per row from LDS
// (bank-swizzled: slot=(lane+row)&31 -> conflict-free write and read).
__global__ __launch_bounds__(256, 4) void dist_part(
    const float* __restrict__ q,      // (B,E)
    const float* __restrict__ q_p,    // (B,E)
    const float* __restrict__ m,      // (B,N,E)
    const float* __restrict__ m_c,    // (B,N,E)
    const float* __restrict__ biases, // (B,N)
    const float* __restrict__ mask,   // (B,N)
    const float* __restrict__ A1,     // (E)
    const float* __restrict__ A2,     // (E)
    float* __restrict__ xs_ws,        // (B,N) softmax logits -> d_ws
    float* __restrict__ os_out)       // (B,N) out_dist*mask  -> d_out
{
    __shared__ float part[2 * HALF * 32];  // [arr][row][slot] 25.6 KB
    __shared__ float s_l[Ec], n2u_l[Ec], tc_l[Ec];

    const int b   = blockIdx.x;
    const int c   = blockIdx.y;          // half of the batch: rows 100c..
    const int tid = threadIdx.x;
    const int w    = tid >> 6;
    const int lane = tid & 63;

    // Phase 0: per-batch expansion vectors.
    if (tid < Ec) {
        const float a1 = A1[tid], a2 = A2[tid];
        const float qq = q[(size_t)b * Ec + tid];
        const float qp = q_p[(size_t)b * Ec + tid];
        const float a1s = a1 * a1, a2s = a2 * a2;
        s_l[tid]   = a1s + a2s;
        n2u_l[tid] = -2.f * (a1s * qq + a2s * qp);
        tc_l[tid]  = a1s * qq * qq + a2s * qp * qp;
    }
    __syncthreads();

    // Phase 1: stream.
    const int arr  = w >> 1;     // 0: m, 1: m_c
    const int half = w & 1;      // which 50-row half of this block's 100 rows
    const int e0   = (lane & 31) * 4;

    const vfloat4 s4 = *reinterpret_cast<const vfloat4*>(&s_l[e0]);
    const vfloat4 u4 = *reinterpret_cast<const vfloat4*>(&n2u_l[e0]);

    const float* src = (arr ? m_c : m)
        + ((size_t)b * Nc + (size_t)c * HALF + half * 50) * Ec + lane * 4;
    const int lr0 = half * 50 + (lane >> 5);  // local row at iter 0 (0..99)
    float* pbase = &part[arr * HALF * 32];
    const int l5 = lane & 31;

    for (int i0 = 0; i0 < ITER; i0 += 5) {
        vfloat4 v[5];
#pragma unroll
        for (int k = 0; k < 5; ++k)
            v[k] = *reinterpret_cast<const vfloat4*>(src + (size_t)(i0 + k) * 256);
#pragma unroll
        for (int k = 0; k < 5; ++k) {
            float p;
            p = v[k].x * fmaf(s4.x, v[k].x, u4.x);
            p = fmaf(v[k].y, fmaf(s4.y, v[k].y, u4.y), p);
            p = fmaf(v[k].z, fmaf(s4.z, v[k].z, u4.z), p);
            p = fmaf(v[k].w, fmaf(s4.w, v[k].w, u4.w), p);
            const int lr   = lr0 + 2 * (i0 + k);
            const int slot = (l5 + lr) & 31;        // bank swizzle
            pbase[lr * 32 + slot] = p;
        }
    }
    __syncthreads();

    // Phase 2: per-row reduction of 32 lane-partials + epilogue.
    float C = 0.f;
#pragma unroll 16
    for (int e = 0; e < Ec; ++e) C += tc_l[e];   // broadcast reads

    if (tid < HALF) {                 // att rows
        const int r = tid, n = c * HALF + r;
        float ssum = 0.f;
#pragma unroll 8
        for (int i = 0; i < 32; ++i) ssum += part[r * 32 + ((i + r) & 31)];
        const float bb = biases[(size_t)b * Nc + n];
        const float mk = mask[(size_t)b * Nc + n];
        xs_ws[(size_t)b * Nc + n] = -(C + ssum + 2.f * bb) * mk;
    } else if (tid >= 128 && tid < 128 + HALF) {  // out rows
        const int r = tid - 128, n = c * HALF + r;
        float ssum = 0.f;
#pragma unroll 8
        for (int i = 0; i < 32; ++i)
            ssum += part[HALF * 32 + r * 32 + ((i + r) & 31)];
        const float bb = biases[(size_t)b * Nc + n];
        const float mk = mask[(size_t)b * Nc + n];
        os_out[(size_t)b * Nc + n] = (C + ssum + 2.f * bb) * mk;
    }
}

// K2: one block per batch; softmax over the 200 logits, scale os, write out.
__global__ __launch_bounds__(256) void softmax_fin(
    const float* __restrict__ xs_ws,  // (B,N) logits
    float* __restrict__ out)          // (B,N) in: out_dist*mask, out: result
{
    const int b   = blockIdx.x;
    const int tid = threadIdx.x;
    __shared__ float red_s[8];

    const float x  = (tid < Nc) ? xs_ws[(size_t)b * Nc + tid] : -INFINITY;
    const float os = (tid < Nc) ? out[(size_t)b * Nc + tid]   : 0.f;

    float wmax = x;
#pragma unroll
    for (int off = 32; off > 0; off >>= 1)
        wmax = fmaxf(wmax, __shfl_xor(wmax, off));
    if ((tid & 63) == 0) red_s[tid >> 6] = wmax;
    __syncthreads();
    const float gmax = fmaxf(fmaxf(red_s[0], red_s[1]), fmaxf(red_s[2], red_s[3]));

    const float ex = (tid < Nc) ? expf(x - gmax) : 0.f;
    float wsum = ex;
#pragma unroll
    for (int off = 32; off > 0; off >>= 1)
        wsum += __shfl_xor(wsum, off);
    if ((tid & 63) == 0) red_s[4 + (tid >> 6)] = wsum;
    __syncthreads();
    const float gsum = (red_s[4] + red_s[5]) + (red_s[6] + red_s[7]);

    if (tid < Nc)
        out[(size_t)b * Nc + tid] = os * (ex / gsum);
}

extern "C" void kernel_launch(void* const* d_in, const int* in_sizes, int n_in,
                              void* d_out, int out_size, void* d_ws, size_t ws_size,
                              hipStream_t stream) {
    const float* q      = (const float*)d_in[0];
    const float* q_p    = (const float*)d_in[1];
    const float* m      = (const float*)d_in[2];
    const float* m_c    = (const float*)d_in[3];
    const float* A1     = (const float*)d_in[4];
    const float* A2     = (const float*)d_in[5];
    const float* biases = (const float*)d_in[6];
    const float* mask   = (const float*)d_in[7];
    float* out   = (float*)d_out;
    float* xs_ws = (float*)d_ws;   // Bc*Nc floats = 800 KiB

    dim3 grid1(Bc, 2);
    dist_part<<<grid1, 256, 0, stream>>>(q, q_p, m, m_c, biases, mask, A1, A2,
                                         xs_ws, out);
    softmax_fin<<<Bc, 256, 0, stream>>>(xs_ws, out);
}